// Round 2
// baseline (2048.324 us; speedup 1.0000x reference)
//
#include <hip/hip_runtime.h>
#include <math.h>

#define B_IMG 16
#define HH 112
#define WW_ 112
#define CC 128
#define LL (HH*WW_)            // 12544
#define NWIN 256               // windows per image (16x16)
#define BWIN (B_IMG*NWIN)      // 4096
#define NTOK 49
#define NROWS (BWIN*NTOK)      // 200704
#define NHEADS 4
#define HD 32
#define SCALE 0.1767766952966369f   // 1/sqrt(32)
#define SHIFT_ 3
#define CHUNKS 8
#define CROWS (NROWS/CHUNKS)   // 25088 rows per chunk
#define CWIN  (BWIN/CHUNKS)    // 512 windows per chunk

// ---------------------------------------------------------------- wave reduce
__device__ __forceinline__ float wave_sum(float v) {
#pragma unroll
  for (int off = 32; off >= 1; off >>= 1) v += __shfl_xor(v, off, 64);
  return v;
}

// ---------------------------------------------------------------- LayerNorm
// GATHER=true: output row r is window-partitioned/rolled; read source pixel.
// GATHER=false: plain row-to-row LN (LN2).
template<bool GATHER>
__global__ __launch_bounds__(256) void ln_kernel(
    const float* __restrict__ X, const float* __restrict__ g,
    const float* __restrict__ b, float* __restrict__ Y)
{
  int wid  = threadIdx.x >> 6;
  int lane = threadIdx.x & 63;
  int r = blockIdx.x * 4 + wid;          // output row
  size_t src;
  if (GATHER) {
    int win = r / NTOK, n = r % NTOK;
    int bi = win >> 8, wi = win & 255;
    int wh = wi >> 4, wwi = wi & 15;
    int ii = n / 7, jj = n % 7;
    int hp = wh * 7 + ii, wp = wwi * 7 + jj;
    int sh = (hp + SHIFT_) % HH, sw = (wp + SHIFT_) % WW_;   // roll(-3) gather
    src = ((size_t)bi * LL + (size_t)sh * WW_ + sw) * CC;
  } else {
    src = (size_t)r * CC;
  }
  float v0 = X[src + lane];
  float v1 = X[src + 64 + lane];
  float mean = wave_sum(v0 + v1) * (1.f / CC);
  float d0 = v0 - mean, d1 = v1 - mean;
  float var = wave_sum(d0 * d0 + d1 * d1) * (1.f / CC);
  float rstd = rsqrtf(var + 1e-5f);
  size_t dst = (size_t)r * CC;
  Y[dst + lane]      = d0 * rstd * g[lane]      + b[lane];
  Y[dst + 64 + lane] = d1 * rstd * g[lane + 64] + b[lane + 64];
}

// ---------------------------------------------------------------- GEMM
// C[m][n] = sum_k A[m][k] * W[n][k] + bias[n]  (+ epilogue)
// M is the block-local row count; row0 translates to global rows for EPI_PROJ.
enum { EPI_BIAS = 0, EPI_GELU = 1, EPI_RES = 2, EPI_PROJ = 3 };

template<int EPI>
__global__ __launch_bounds__(256) void gemm_kernel(
    const float* __restrict__ A, const float* __restrict__ W,
    const float* __restrict__ bias, const float* __restrict__ aux,
    float* __restrict__ Cout, int N, int K)
{
  __shared__ float As[16][68];
  __shared__ float Bs[16][68];
  int t = threadIdx.x;
  int m0 = blockIdx.x * 64, n0 = blockIdx.y * 64;
  int lrow = t >> 2;               // 0..63
  int lkq  = (t & 3) << 2;         // 0,4,8,12
  int tx = t & 15, ty = t >> 4;    // 16x16 thread grid, 4x4 micro-tile
  float acc[4][4] = {};
  const float* Ap = A + (size_t)(m0 + lrow) * K + lkq;
  const float* Wp = W + (size_t)(n0 + lrow) * K + lkq;
  for (int k0 = 0; k0 < K; k0 += 16) {
    float4 av = *(const float4*)(Ap + k0);
    float4 bv = *(const float4*)(Wp + k0);
    As[lkq + 0][lrow] = av.x; As[lkq + 1][lrow] = av.y;
    As[lkq + 2][lrow] = av.z; As[lkq + 3][lrow] = av.w;
    Bs[lkq + 0][lrow] = bv.x; Bs[lkq + 1][lrow] = bv.y;
    Bs[lkq + 2][lrow] = bv.z; Bs[lkq + 3][lrow] = bv.w;
    __syncthreads();
#pragma unroll
    for (int kk = 0; kk < 16; ++kk) {
      float a[4], bb[4];
#pragma unroll
      for (int i = 0; i < 4; ++i) a[i] = As[kk][ty * 4 + i];
#pragma unroll
      for (int j = 0; j < 4; ++j) bb[j] = Bs[kk][tx * 4 + j];
#pragma unroll
      for (int i = 0; i < 4; ++i)
#pragma unroll
        for (int j = 0; j < 4; ++j)
          acc[i][j] = fmaf(a[i], bb[j], acc[i][j]);
    }
    __syncthreads();
  }
#pragma unroll
  for (int i = 0; i < 4; ++i) {
    int m = m0 + ty * 4 + i;
#pragma unroll
    for (int j = 0; j < 4; ++j) {
      int n = n0 + tx * 4 + j;
      float v = acc[i][j] + bias[n];
      if (EPI == EPI_GELU) {
        v = 0.5f * v * (1.f + erff(v * 0.70710678118654752f));
        Cout[(size_t)m * N + n] = v;
      } else if (EPI == EPI_RES) {
        // in-place residual: aux and Cout may alias (same element, same thread)
        Cout[(size_t)m * N + n] = v + aux[(size_t)m * N + n];
      } else if (EPI == EPI_PROJ) {
        // window-reverse + roll(+3,+3) + shortcut add, scatter into x1 (d_out)
        int win = m / NTOK, nn = m % NTOK;
        int bi = win >> 8, wi = win & 255;
        int wh = wi >> 4, wwi = wi & 15;
        int ii = nn / 7, jj = nn % 7;
        int hp = wh * 7 + ii, wp = wwi * 7 + jj;
        int oh = (hp + SHIFT_) % HH, ow = (wp + SHIFT_) % WW_;
        size_t idx = ((size_t)bi * LL + (size_t)oh * WW_ + ow) * CC + n;
        Cout[idx] = aux[idx] + v;
      } else {
        Cout[(size_t)m * N + n] = v;
      }
    }
  }
}

// ---------------------------------------------------------------- Attention
// one block per (local window, head); qkv is the current chunk's buffer.
// Writes o IN-PLACE over bufA's rows for this window (xw dead after qkv GEMM).
__global__ __launch_bounds__(128) void attn_kernel(
    const float* __restrict__ qkv, const float* __restrict__ mask,
    const float* __restrict__ table, float* __restrict__ O, int win_off)
{
  int win_l = blockIdx.x >> 2;          // local window in chunk
  int h     = blockIdx.x & 3;
  int win_g = win_off + win_l;          // global window id
  __shared__ float q[NTOK][33], k[NTOK][33], v[NTOK][33];
  __shared__ float S[NTOK][NTOK];
  int t = threadIdx.x;
  for (int idx = t; idx < NTOK * HD; idx += 128) {
    int n = idx >> 5, d = idx & 31;
    size_t base = ((size_t)win_l * NTOK + n) * 384 + h * HD + d;
    q[n][d] = qkv[base] * SCALE;
    k[n][d] = qkv[base + 128];
    v[n][d] = qkv[base + 256];
  }
  __syncthreads();
  const float* mrow = mask + (size_t)(win_g & 255) * NTOK * NTOK;
  for (int e = t; e < NTOK * NTOK; e += 128) {
    int i = e / NTOK, j = e % NTOK;
    float s = 0.f;
#pragma unroll
    for (int d = 0; d < HD; ++d) s = fmaf(q[i][d], k[j][d], s);
    int yi = i / 7, xi = i % 7, yj = j / 7, xj = j % 7;
    int ridx = (yi - yj + 6) * 13 + (xi - xj + 6);
    s += table[ridx * 4 + h] + mrow[e];
    S[i][j] = s;
  }
  __syncthreads();
  for (int r = t; r < NTOK; r += 128) {
    float mx = -1e30f;
    for (int j = 0; j < NTOK; ++j) mx = fmaxf(mx, S[r][j]);
    float sum = 0.f;
    for (int j = 0; j < NTOK; ++j) { float e2 = expf(S[r][j] - mx); S[r][j] = e2; sum += e2; }
    float inv = 1.f / sum;
    for (int j = 0; j < NTOK; ++j) S[r][j] *= inv;
  }
  __syncthreads();
  for (int e = t; e < NTOK * HD; e += 128) {
    int i = e >> 5, d = e & 31;
    float s = 0.f;
    for (int j = 0; j < NTOK; ++j) s = fmaf(S[i][j], v[j][d], s);
    O[((size_t)win_g * NTOK + i) * CC + h * HD + d] = s;
  }
}

// ---------------------------------------------------------------- launch
extern "C" void kernel_launch(void* const* d_in, const int* in_sizes, int n_in,
                              void* d_out, int out_size, void* d_ws, size_t ws_size,
                              hipStream_t stream) {
  const float* x        = (const float*)d_in[0];
  const float* attnmask = (const float*)d_in[3];
  const float* ln1_g    = (const float*)d_in[4];
  const float* ln1_b    = (const float*)d_in[5];
  const float* qkv_w    = (const float*)d_in[6];
  const float* qkv_b    = (const float*)d_in[7];
  const float* table    = (const float*)d_in[8];
  const float* proj_w   = (const float*)d_in[9];
  const float* proj_b   = (const float*)d_in[10];
  const float* ln2_g    = (const float*)d_in[11];
  const float* ln2_b    = (const float*)d_in[12];
  const float* fc1_w    = (const float*)d_in[13];
  const float* fc1_b    = (const float*)d_in[14];
  const float* fc2_w    = (const float*)d_in[15];
  const float* fc2_b    = (const float*)d_in[16];
  float* out = (float*)d_out;                        // doubles as x1 storage

  // workspace: bufA = NROWS*128 floats (102.8 MB), bufB = CROWS*512 floats (51.4 MB)
  float* wsf  = (float*)d_ws;
  const size_t ROWSZ = (size_t)NROWS * CC;
  float* bufA = wsf;                                 // xw -> o -> f
  float* bufB = wsf + ROWSZ;                         // per-chunk qkv / h1

  // 1. LN1 + roll + window partition: x -> bufA
  ln_kernel<true><<<NROWS / 4, 256, 0, stream>>>(x, ln1_g, ln1_b, bufA);

  // 2+3. per chunk: qkv GEMM (bufA_i -> bufB), attention (bufB -> bufA_i in place)
  for (int c = 0; c < CHUNKS; ++c) {
    const float* Ain = bufA + (size_t)c * CROWS * CC;
    dim3 g(CROWS / 64, 384 / 64);
    gemm_kernel<EPI_BIAS><<<g, 256, 0, stream>>>(Ain, qkv_w, qkv_b, nullptr, bufB, 384, 128);
    attn_kernel<<<CWIN * NHEADS, 128, 0, stream>>>(bufB, attnmask, table, bufA, c * CWIN);
  }

  // 4. proj GEMM + reverse/roll/residual scatter -> d_out (x1)
  {
    dim3 g(NROWS / 64, 128 / 64);
    gemm_kernel<EPI_PROJ><<<g, 256, 0, stream>>>(bufA, proj_w, proj_b, x, out, 128, 128);
  }
  // 5. LN2: d_out -> bufA (f)
  ln_kernel<false><<<NROWS / 4, 256, 0, stream>>>(out, ln2_g, ln2_b, bufA);

  // 6+7. per chunk: fc1+GELU (bufA_i -> bufB), fc2+residual (bufB -> d_out_i in place)
  for (int c = 0; c < CHUNKS; ++c) {
    const float* Ain = bufA + (size_t)c * CROWS * CC;
    float* Oc = out + (size_t)c * CROWS * CC;
    dim3 g1(CROWS / 64, 512 / 64);
    gemm_kernel<EPI_GELU><<<g1, 256, 0, stream>>>(Ain, fc1_w, fc1_b, nullptr, bufB, 512, 128);
    dim3 g2(CROWS / 64, 128 / 64);
    gemm_kernel<EPI_RES><<<g2, 256, 0, stream>>>(bufB, fc2_w, fc2_b, Oc, Oc, 128, 512);
  }
}

// Round 3
// 972.117 us; speedup vs baseline: 2.1071x; 2.1071x over previous
//
#include <hip/hip_runtime.h>
#include <hip/hip_bf16.h>
#include <math.h>

#define B_IMG 16
#define HH 112
#define WW_ 112
#define CC 128
#define LL (HH*WW_)            // 12544
#define BWIN 4096
#define NTOK 49
#define NROWS (BWIN*NTOK)      // 200704
#define HD 32
#define SCALE 0.1767766952966369f   // 1/sqrt(32)
#define SHIFT_ 3

typedef short bf16x8 __attribute__((ext_vector_type(8)));
typedef float f32x4 __attribute__((ext_vector_type(4)));
typedef unsigned short ushort_t;

// ---------------------------------------------------------------- helpers
__device__ __forceinline__ float wave_sum(float v) {
#pragma unroll
  for (int off = 32; off >= 1; off >>= 1) v += __shfl_xor(v, off, 64);
  return v;
}

__global__ __launch_bounds__(256) void castw_kernel(const float* __restrict__ w,
                                                    __hip_bfloat16* __restrict__ o, int n) {
  int i = blockIdx.x * 256 + threadIdx.x;
  if (i < n) o[i] = __float2bfloat16(w[i]);
}

// ---------------------------------------------------------------- LayerNorm (fp32 in, bf16 out)
template<bool GATHER>
__global__ __launch_bounds__(256) void ln_kernel(
    const float* __restrict__ X, const float* __restrict__ g,
    const float* __restrict__ b, __hip_bfloat16* __restrict__ Y)
{
  int wid  = threadIdx.x >> 6;
  int lane = threadIdx.x & 63;
  int r = blockIdx.x * 4 + wid;
  size_t src;
  if (GATHER) {
    int win = r / NTOK, n = r % NTOK;
    int bi = win >> 8, wi = win & 255;
    int wh = wi >> 4, wwi = wi & 15;
    int ii = n / 7, jj = n % 7;
    int hp = wh * 7 + ii, wp = wwi * 7 + jj;
    int sh = (hp + SHIFT_) % HH, sw = (wp + SHIFT_) % WW_;   // roll(-3) gather
    src = ((size_t)bi * LL + (size_t)sh * WW_ + sw) * CC;
  } else {
    src = (size_t)r * CC;
  }
  float v0 = X[src + lane];
  float v1 = X[src + 64 + lane];
  float mean = wave_sum(v0 + v1) * (1.f / CC);
  float d0 = v0 - mean, d1 = v1 - mean;
  float var = wave_sum(d0 * d0 + d1 * d1) * (1.f / CC);
  float rstd = rsqrtf(var + 1e-5f);
  size_t dst = (size_t)r * CC;
  Y[dst + lane]      = __float2bfloat16(d0 * rstd * g[lane]      + b[lane]);
  Y[dst + 64 + lane] = __float2bfloat16(d1 * rstd * g[lane + 64] + b[lane + 64]);
}

// ---------------------------------------------------------------- bf16 MFMA GEMM
// C[m][n] = sum_k A[m][k]*W[n][k] + bias[n]  (+ epilogue). A,W bf16; acc fp32.
// 128x128 tile, 256 thr = 4 waves (2x2), each wave 64x64 via 4x4 of 16x16x32.
enum { EPI_BIAS = 0, EPI_GELU = 1, EPI_RES = 2, EPI_PROJ = 3 };
#define LDSW 136   // 128 + 8 pad: keeps 16B alignment, breaks bank-phase

template<int EPI>
__global__ __launch_bounds__(256, 2) void gemm_bf16(
    const ushort_t* __restrict__ A, const ushort_t* __restrict__ W,
    const float* __restrict__ bias, const float* __restrict__ aux,
    void* __restrict__ outp, int N, int K)
{
  __shared__ ushort_t As[128 * LDSW];
  __shared__ ushort_t Bs[128 * LDSW];
  int t = threadIdx.x;
  int lane = t & 63;
  int quad = lane >> 4;
  int l16  = lane & 15;
  int wr = (t >> 7) * 64;        // wave row offset in tile
  int wc = ((t >> 6) & 1) * 64;  // wave col offset in tile
  int m0 = blockIdx.x * 128, n0 = blockIdx.y * 128;

  f32x4 acc[4][4];
#pragma unroll
  for (int i = 0; i < 4; ++i)
#pragma unroll
    for (int j = 0; j < 4; ++j) acc[i][j] = (f32x4){0.f, 0.f, 0.f, 0.f};

  for (int kb = 0; kb < K; kb += 128) {
    if (kb) __syncthreads();
    // stage 128x128 bf16 panels of A and W
#pragma unroll
    for (int p = 0; p < 8; ++p) {
      int lin = p * 256 + t;
      int row = lin >> 4;
      int col = (lin & 15) * 8;
      uint4 av = *(const uint4*)(A + (size_t)(m0 + row) * K + kb + col);
      uint4 bv = *(const uint4*)(W + (size_t)(n0 + row) * K + kb + col);
      *(uint4*)&As[row * LDSW + col] = av;
      *(uint4*)&Bs[row * LDSW + col] = bv;
    }
    __syncthreads();
#pragma unroll
    for (int ks = 0; ks < 4; ++ks) {
      int k0 = ks * 32 + quad * 8;
      bf16x8 af[4], bf[4];
#pragma unroll
      for (int i = 0; i < 4; ++i)
        af[i] = *(const bf16x8*)&As[(wr + i * 16 + l16) * LDSW + k0];
#pragma unroll
      for (int j = 0; j < 4; ++j)
        bf[j] = *(const bf16x8*)&Bs[(wc + j * 16 + l16) * LDSW + k0];
#pragma unroll
      for (int i = 0; i < 4; ++i)
#pragma unroll
        for (int j = 0; j < 4; ++j)
          acc[i][j] = __builtin_amdgcn_mfma_f32_16x16x32_bf16(af[i], bf[j], acc[i][j], 0, 0, 0);
    }
  }

  // epilogue: C/D layout col=lane&15, row=quad*4+reg
#pragma unroll
  for (int i = 0; i < 4; ++i) {
#pragma unroll
    for (int j = 0; j < 4; ++j) {
      int n = n0 + wc + j * 16 + l16;
      float bn = bias[n];
#pragma unroll
      for (int reg = 0; reg < 4; ++reg) {
        int m = m0 + wr + i * 16 + quad * 4 + reg;
        float v = acc[i][j][reg] + bn;
        if (EPI == EPI_BIAS) {
          ((__hip_bfloat16*)outp)[(size_t)m * N + n] = __float2bfloat16(v);
        } else if (EPI == EPI_GELU) {
          v = 0.5f * v * (1.f + erff(v * 0.70710678118654752f));
          ((__hip_bfloat16*)outp)[(size_t)m * N + n] = __float2bfloat16(v);
        } else if (EPI == EPI_RES) {
          // in-place residual (aux aliases outp; same element, same thread)
          ((float*)outp)[(size_t)m * N + n] = v + aux[(size_t)m * N + n];
        } else { // EPI_PROJ: window-reverse + roll(+3,+3) + shortcut, scatter fp32
          int win = m / NTOK, nn = m % NTOK;
          int bi = win >> 8, wi = win & 255;
          int wh = wi >> 4, wwi = wi & 15;
          int ii = nn / 7, jj = nn % 7;
          int hp = wh * 7 + ii, wp = wwi * 7 + jj;
          int oh = (hp + SHIFT_) % HH, ow = (wp + SHIFT_) % WW_;
          size_t idx = ((size_t)bi * LL + (size_t)oh * WW_ + ow) * CC + n;
          ((float*)outp)[idx] = aux[idx] + v;
        }
      }
    }
  }
}

// ---------------------------------------------------------------- Attention (bf16 qkv in, bf16 o out)
__global__ __launch_bounds__(128) void attn_kernel(
    const __hip_bfloat16* __restrict__ qkv, const float* __restrict__ mask,
    const float* __restrict__ table, __hip_bfloat16* __restrict__ O, int win_off)
{
  int win_l = blockIdx.x >> 2;
  int h     = blockIdx.x & 3;
  int win_g = win_off + win_l;
  __shared__ float q[NTOK][33], k[NTOK][33], v[NTOK][33];
  __shared__ float S[NTOK][NTOK];
  int t = threadIdx.x;
  for (int idx = t; idx < NTOK * HD; idx += 128) {
    int n = idx >> 5, d = idx & 31;
    size_t base = ((size_t)win_l * NTOK + n) * 384 + h * HD + d;
    q[n][d] = __bfloat162float(qkv[base]) * SCALE;
    k[n][d] = __bfloat162float(qkv[base + 128]);
    v[n][d] = __bfloat162float(qkv[base + 256]);
  }
  __syncthreads();
  const float* mrow = mask + (size_t)(win_g & 255) * NTOK * NTOK;
  for (int e = t; e < NTOK * NTOK; e += 128) {
    int i = e / NTOK, j = e % NTOK;
    float s = 0.f;
#pragma unroll
    for (int d = 0; d < HD; ++d) s = fmaf(q[i][d], k[j][d], s);
    int yi = i / 7, xi = i % 7, yj = j / 7, xj = j % 7;
    int ridx = (yi - yj + 6) * 13 + (xi - xj + 6);
    s += table[ridx * 4 + h] + mrow[e];
    S[i][j] = s;
  }
  __syncthreads();
  for (int r = t; r < NTOK; r += 128) {
    float mx = -1e30f;
    for (int j = 0; j < NTOK; ++j) mx = fmaxf(mx, S[r][j]);
    float sum = 0.f;
    for (int j = 0; j < NTOK; ++j) { float e2 = expf(S[r][j] - mx); S[r][j] = e2; sum += e2; }
    float inv = 1.f / sum;
    for (int j = 0; j < NTOK; ++j) S[r][j] *= inv;
  }
  __syncthreads();
  for (int e = t; e < NTOK * HD; e += 128) {
    int i = e >> 5, d = e & 31;
    float s = 0.f;
    for (int j = 0; j < NTOK; ++j) s = fmaf(S[i][j], v[j][d], s);
    O[((size_t)win_g * NTOK + i) * CC + h * HD + d] = __float2bfloat16(s);
  }
}

// ---------------------------------------------------------------- launch
extern "C" void kernel_launch(void* const* d_in, const int* in_sizes, int n_in,
                              void* d_out, int out_size, void* d_ws, size_t ws_size,
                              hipStream_t stream) {
  const float* x        = (const float*)d_in[0];
  const float* attnmask = (const float*)d_in[3];
  const float* ln1_g    = (const float*)d_in[4];
  const float* ln1_b    = (const float*)d_in[5];
  const float* qkv_w    = (const float*)d_in[6];
  const float* qkv_b    = (const float*)d_in[7];
  const float* table    = (const float*)d_in[8];
  const float* proj_w   = (const float*)d_in[9];
  const float* proj_b   = (const float*)d_in[10];
  const float* ln2_g    = (const float*)d_in[11];
  const float* ln2_b    = (const float*)d_in[12];
  const float* fc1_w    = (const float*)d_in[13];
  const float* fc1_b    = (const float*)d_in[14];
  const float* fc2_w    = (const float*)d_in[15];
  const float* fc2_b    = (const float*)d_in[16];
  float* out = (float*)d_out;   // x1 lives here

  // ws layout (bf16): bufA 25.69M elems | bufB 38.54M elems | weights
  __hip_bfloat16* bufA = (__hip_bfloat16*)d_ws;                 // xw -> o -> f
  __hip_bfloat16* bufB = bufA + (size_t)NROWS * CC;             // qkv/h1 chunks
  __hip_bfloat16* wq   = bufB + (size_t)(NROWS / 2) * 384;
  __hip_bfloat16* wp   = wq + 384 * 128;
  __hip_bfloat16* w1   = wp + 128 * 128;
  __hip_bfloat16* w2   = w1 + 512 * 128;

  // 0. cast weights to bf16
  castw_kernel<<<(384 * 128 + 255) / 256, 256, 0, stream>>>(qkv_w, wq, 384 * 128);
  castw_kernel<<<(128 * 128 + 255) / 256, 256, 0, stream>>>(proj_w, wp, 128 * 128);
  castw_kernel<<<(512 * 128 + 255) / 256, 256, 0, stream>>>(fc1_w, w1, 512 * 128);
  castw_kernel<<<(128 * 512 + 255) / 256, 256, 0, stream>>>(fc2_w, w2, 128 * 512);

  // 1. LN1 + roll + window partition: x -> bufA (bf16)
  ln_kernel<true><<<NROWS / 4, 256, 0, stream>>>(x, ln1_g, ln1_b, bufA);

  // 2+3. qkv GEMM + attention, 2 chunks of M/2 rows (2048 windows each)
  for (int c = 0; c < 2; ++c) {
    const int MC = NROWS / 2;           // 100352
    const ushort_t* Ain = (const ushort_t*)(bufA + (size_t)c * MC * CC);
    dim3 g(MC / 128, 384 / 128);
    gemm_bf16<EPI_BIAS><<<g, 256, 0, stream>>>(Ain, (const ushort_t*)wq, qkv_b,
                                               nullptr, bufB, 384, 128);
    attn_kernel<<<2048 * 4, 128, 0, stream>>>(bufB, attnmask, table, bufA, c * 2048);
  }

  // 4. proj GEMM + reverse/roll/residual scatter -> d_out (fp32 x1)
  {
    dim3 g(NROWS / 128, 1);
    gemm_bf16<EPI_PROJ><<<g, 256, 0, stream>>>((const ushort_t*)bufA, (const ushort_t*)wp,
                                               proj_b, x, out, 128, 128);
  }
  // 5. LN2: d_out -> bufA (bf16 f)
  ln_kernel<false><<<NROWS / 4, 256, 0, stream>>>(out, ln2_g, ln2_b, bufA);

  // 6+7. fc1+GELU, fc2+residual, 4 chunks of M/4 rows
  for (int c = 0; c < 4; ++c) {
    const int MC = NROWS / 4;           // 50176
    const ushort_t* Ain = (const ushort_t*)(bufA + (size_t)c * MC * CC);
    float* Oc = out + (size_t)c * MC * CC;
    dim3 g1(MC / 128, 512 / 128);
    gemm_bf16<EPI_GELU><<<g1, 256, 0, stream>>>(Ain, (const ushort_t*)w1, fc1_b,
                                                nullptr, bufB, 512, 128);
    dim3 g2(MC / 128, 1);
    gemm_bf16<EPI_RES><<<g2, 256, 0, stream>>>((const ushort_t*)bufB, (const ushort_t*)w2,
                                               fc2_b, Oc, Oc, 128, 512);
  }
}